// Round 3
// baseline (52.476 us; speedup 1.0000x reference)
//
#include <hip/hip_runtime.h>

#define NLOC (1024 * 1024)          // H*W per head
#define HALF_PI 1.57079632679489662f
#define THRESH 0.9f

__device__ __forceinline__ float sigmoidf_(float x) {
    return 1.0f / (1.0f + __expf(-x));
}

// Per block: 256 threads = 4 INDEPENDENT waves, no __syncthreads.
// Each wave owns 256 consecutive locations (4 per lane) of one head and a
// private 8 KB LDS slice used to transpose boxes, then scores, into
// lane-contiguous float4 global stores. Intra-wave LDS ordering is handled
// by the compiler (lgkmcnt); waves never interact.
__global__ __launch_bounds__(256) void decode_kernel(
    const float* __restrict__ obj1, const float* __restrict__ cs1, const float* __restrict__ bb1,
    const float* __restrict__ obj2, const float* __restrict__ cs2, const float* __restrict__ bb2,
    const float* __restrict__ orients, const float* __restrict__ adims,
    float* __restrict__ out)
{
    __shared__ float lds[4 * 2048];                 // 8 KB per wave, 32 KB total

    const int tid  = threadIdx.x;
    const int wid  = tid >> 6;                      // wave 0..3
    const int lane = tid & 63;
    const int head = blockIdx.x >> 10;              // 1024 blocks per head (uniform)
    const int blk  = blockIdx.x & 1023;
    const int wl   = (blk << 10) + (wid << 8);      // wave's first location
    const int n0   = wl + (lane << 2);              // lane's first of 4 locations

    float* buf = &lds[wid << 11];                   // this wave's 2048-float slice

    const float* obj = head ? obj2 : obj1;
    const float* cs  = head ? cs2  : cs1;
    const float* bb  = head ? bb2  : bb1;
    const float orient = orients[head];
    const float d0 = adims[0], d1 = adims[1], d2 = adims[2];
    float* ob = out + (size_t)head * 17 * NLOC;

    // ---- loads (16B aligned, coalesced) ----
    float4 o4 = *reinterpret_cast<const float4*>(obj + n0);
    float ov[4] = { o4.x, o4.y, o4.z, o4.w };

    float bbv[7][4];
#pragma unroll
    for (int c = 0; c < 7; ++c) {
        float4 t = *reinterpret_cast<const float4*>(bb + (size_t)c * NLOC + n0);
        bbv[c][0] = t.x; bbv[c][1] = t.y; bbv[c][2] = t.z; bbv[c][3] = t.w;
    }
    float sv[8][4];
#pragma unroll
    for (int c = 0; c < 8; ++c) {
        float4 t = *reinterpret_cast<const float4*>(cs + (size_t)c * NLOC + n0);
        sv[c][0] = t.x; sv[c][1] = t.y; sv[c][2] = t.z; sv[c][3] = t.w;
    }

    // grid coords: all 4 locations share a row (n0 % 4 == 0, W = 1024)
    const float fi  = (float)(n0 >> 10) + 0.5f;
    const float fj0 = (float)(n0 & 1023) + 0.5f;

    float mk_[4];
    float bx[28];
#pragma unroll
    for (int t = 0; t < 4; ++t) {
        float m  = (ov[t] >= THRESH) ? 1.0f : 0.0f;
        mk_[t] = m;
        float fj = fj0 + (float)t;
        bx[t * 7 + 0] = (orient + sigmoidf_(bbv[0][t]) * HALF_PI) * m;
        bx[t * 7 + 1] = (sigmoidf_(bbv[1][t]) + fi) * m;
        bx[t * 7 + 2] = (sigmoidf_(bbv[2][t]) + fj) * m;
        bx[t * 7 + 3] = sigmoidf_(bbv[3][t]) * m;
        bx[t * 7 + 4] = d0 * __expf(bbv[4][t]) * m;
        bx[t * 7 + 5] = d1 * __expf(bbv[5][t]) * m;
        bx[t * 7 + 6] = d2 * __expf(bbv[6][t]) * m;
    }

    // ---- direct stores (already coalesced): obj, mask ----
    *reinterpret_cast<float4*>(ob + (size_t)15 * NLOC + n0) =
        make_float4(ov[0] * mk_[0], ov[1] * mk_[1], ov[2] * mk_[2], ov[3] * mk_[3]);
    *reinterpret_cast<float4*>(ob + (size_t)16 * NLOC + n0) =
        make_float4(mk_[0], mk_[1], mk_[2], mk_[3]);

    // ---- boxes via per-wave LDS transpose (no barrier) ----
    // write: lane -> float4 indices [lane*7, lane*7+7); stride 7 float4s is
    // conflict-free (each float4-bank hit 2x per 16-lane phase).
#pragma unroll
    for (int q = 0; q < 7; ++q)
        *reinterpret_cast<float4*>(&buf[lane * 28 + q * 4]) =
            make_float4(bx[q * 4 + 0], bx[q * 4 + 1], bx[q * 4 + 2], bx[q * 4 + 3]);
    {
        float* gb = ob + (size_t)wl * 7;            // 1792 contiguous floats
#pragma unroll
        for (int q = 0; q < 7; ++q) {
            int w = 4 * (lane + 64 * q);
            *reinterpret_cast<float4*>(gb + w) = *reinterpret_cast<const float4*>(&buf[w]);
        }
    }

    // ---- scores via per-wave LDS transpose, XOR-swizzled (no barrier) ----
    // (reuses buf; compiler orders the ds ops via lgkmcnt — same wave)
#pragma unroll
    for (int q = 0; q < 8; ++q) {
        int t = q >> 1, c0 = (q & 1) * 4;
        float m = mk_[t];
        int f = lane * 8 + q;                // logical float4 index
        int p = f ^ ((f >> 3) & 7);          // swizzled physical index
        *reinterpret_cast<float4*>(&buf[p * 4]) =
            make_float4(sv[c0][t] * m, sv[c0 + 1][t] * m, sv[c0 + 2][t] * m, sv[c0 + 3][t] * m);
    }
    {
        float* gs = ob + (size_t)7 * NLOC + (size_t)wl * 8;   // 2048 contiguous floats
#pragma unroll
        for (int q = 0; q < 8; ++q) {
            int f = lane + 64 * q;           // logical float4 index (contiguous out)
            int p = f ^ ((f >> 3) & 7);
            *reinterpret_cast<float4*>(gs + 4 * f) =
                *reinterpret_cast<const float4*>(&buf[p * 4]);
        }
    }
}

extern "C" void kernel_launch(void* const* d_in, const int* in_sizes, int n_in,
                              void* d_out, int out_size, void* d_ws, size_t ws_size,
                              hipStream_t stream) {
    const float* obj1    = (const float*)d_in[0];
    const float* cs1     = (const float*)d_in[1];
    const float* bb1     = (const float*)d_in[2];
    const float* obj2    = (const float*)d_in[3];
    const float* cs2     = (const float*)d_in[4];
    const float* bb2     = (const float*)d_in[5];
    const float* orients = (const float*)d_in[6];
    const float* adims   = (const float*)d_in[7];
    float* out = (float*)d_out;

    decode_kernel<<<2048, 256, 0, stream>>>(obj1, cs1, bb1, obj2, cs2, bb2,
                                            orients, adims, out);
}

// Round 4
// 46.784 us; speedup vs baseline: 1.1217x; 1.1217x over previous
//
#include <hip/hip_runtime.h>

#define NLOC (1024 * 1024)          // H*W per head
#define HALF_PI 1.57079632679489662f
#define THRESH 0.9f

typedef float v4f __attribute__((ext_vector_type(4)));

__device__ __forceinline__ float sigmoidf_(float x) {
    return 1.0f / (1.0f + __expf(-x));
}

__device__ __forceinline__ void nt_store4(float* p, float a, float b, float c, float d) {
    v4f v = { a, b, c, d };
    __builtin_nontemporal_store(v, reinterpret_cast<v4f*>(p));
}

__device__ __forceinline__ void nt_copy4(float* g, const float* l) {
    v4f v = *reinterpret_cast<const v4f*>(l);
    __builtin_nontemporal_store(v, reinterpret_cast<v4f*>(g));
}

// Persistent grid: 1024 blocks (4/CU, all co-resident: 4 x 32KB = 128KB LDS).
// Block b processes tile b of head 0, then tile b of head 1.
// Per tile: 256 threads x 4 consecutive locations; boxes/scores transposed
// through LDS so every global store is lane-contiguous; all output stores
// are non-temporal (write-once, keep inputs in L3).
__global__ __launch_bounds__(256) void decode_kernel(
    const float* __restrict__ obj1, const float* __restrict__ cs1, const float* __restrict__ bb1,
    const float* __restrict__ obj2, const float* __restrict__ cs2, const float* __restrict__ bb2,
    const float* __restrict__ orients, const float* __restrict__ adims,
    float* __restrict__ out)
{
    __shared__ float lds[8192];                     // 32 KB, reused across phases/iters

    const int tid   = threadIdx.x;
    const int tile0 = (int)blockIdx.x << 10;        // tile start (same for both heads)
    const int n0    = tile0 + (tid << 2);           // this thread's first location
    const float d0 = adims[0], d1 = adims[1], d2 = adims[2];

    // grid coords: all 4 locations share a row (n0 % 4 == 0, W = 1024)
    const float fi  = (float)(n0 >> 10) + 0.5f;
    const float fj0 = (float)(n0 & 1023) + 0.5f;

#pragma unroll 1
    for (int head = 0; head < 2; ++head) {
        const float* obj = head ? obj2 : obj1;
        const float* cs  = head ? cs2  : cs1;
        const float* bb  = head ? bb2  : bb1;
        const float orient = orients[head];
        float* ob = out + (size_t)head * 17 * NLOC;

        // ---- loads (16B aligned, coalesced); issued before the LDS-reuse
        // barrier so iter-2 loads overlap iter-1's draining stores ----
        float4 o4 = *reinterpret_cast<const float4*>(obj + n0);
        float ov[4] = { o4.x, o4.y, o4.z, o4.w };

        float bbv[7][4];
#pragma unroll
        for (int c = 0; c < 7; ++c) {
            float4 t = *reinterpret_cast<const float4*>(bb + (size_t)c * NLOC + n0);
            bbv[c][0] = t.x; bbv[c][1] = t.y; bbv[c][2] = t.z; bbv[c][3] = t.w;
        }
        float sv[8][4];
#pragma unroll
        for (int c = 0; c < 8; ++c) {
            float4 t = *reinterpret_cast<const float4*>(cs + (size_t)c * NLOC + n0);
            sv[c][0] = t.x; sv[c][1] = t.y; sv[c][2] = t.z; sv[c][3] = t.w;
        }

        float mk_[4];
        float bx[28];
#pragma unroll
        for (int t = 0; t < 4; ++t) {
            float m  = (ov[t] >= THRESH) ? 1.0f : 0.0f;
            mk_[t] = m;
            float fj = fj0 + (float)t;
            bx[t * 7 + 0] = (orient + sigmoidf_(bbv[0][t]) * HALF_PI) * m;
            bx[t * 7 + 1] = (sigmoidf_(bbv[1][t]) + fi) * m;
            bx[t * 7 + 2] = (sigmoidf_(bbv[2][t]) + fj) * m;
            bx[t * 7 + 3] = sigmoidf_(bbv[3][t]) * m;
            bx[t * 7 + 4] = d0 * __expf(bbv[4][t]) * m;
            bx[t * 7 + 5] = d1 * __expf(bbv[5][t]) * m;
            bx[t * 7 + 6] = d2 * __expf(bbv[6][t]) * m;
        }

        // ---- direct stores (already coalesced): obj, mask ----
        nt_store4(ob + (size_t)15 * NLOC + n0,
                  ov[0] * mk_[0], ov[1] * mk_[1], ov[2] * mk_[2], ov[3] * mk_[3]);
        nt_store4(ob + (size_t)16 * NLOC + n0, mk_[0], mk_[1], mk_[2], mk_[3]);

        if (head) __syncthreads();                  // LDS reuse across iterations

        // ---- phase A: boxes via LDS transpose ----
        // write stride 28 words: banks repeat every 8 lanes -> 2 words/bank
        // per 16-lane phase (b128 minimum, conflict-free).
#pragma unroll
        for (int q = 0; q < 7; ++q)
            *reinterpret_cast<float4*>(&lds[tid * 28 + q * 4]) =
                make_float4(bx[q * 4 + 0], bx[q * 4 + 1], bx[q * 4 + 2], bx[q * 4 + 3]);
        __syncthreads();
        {
            float* gb = ob + (size_t)tile0 * 7;     // 7168 contiguous floats
#pragma unroll
            for (int q = 0; q < 7; ++q) {
                int w = 4 * (tid + 256 * q);
                nt_copy4(gb + w, &lds[w]);
            }
        }
        __syncthreads();

        // ---- phase B: scores via LDS transpose (XOR swizzle: raw stride-32
        // float4 writes would be a 16-way bank conflict) ----
#pragma unroll
        for (int q = 0; q < 8; ++q) {
            int t = q >> 1, c0 = (q & 1) * 4;
            float m = mk_[t];
            int f = tid * 8 + q;                 // logical float4 index
            int p = f ^ ((f >> 3) & 7);          // swizzled physical index
            *reinterpret_cast<float4*>(&lds[p * 4]) =
                make_float4(sv[c0][t] * m, sv[c0 + 1][t] * m,
                            sv[c0 + 2][t] * m, sv[c0 + 3][t] * m);
        }
        __syncthreads();
        {
            float* gs = ob + (size_t)7 * NLOC + (size_t)tile0 * 8;  // 8192 floats
#pragma unroll
            for (int q = 0; q < 8; ++q) {
                int f = tid + 256 * q;           // logical float4 index (contiguous)
                int p = f ^ ((f >> 3) & 7);
                nt_copy4(gs + 4 * f, &lds[p * 4]);
            }
        }
    }
}

extern "C" void kernel_launch(void* const* d_in, const int* in_sizes, int n_in,
                              void* d_out, int out_size, void* d_ws, size_t ws_size,
                              hipStream_t stream) {
    const float* obj1    = (const float*)d_in[0];
    const float* cs1     = (const float*)d_in[1];
    const float* bb1     = (const float*)d_in[2];
    const float* obj2    = (const float*)d_in[3];
    const float* cs2     = (const float*)d_in[4];
    const float* bb2     = (const float*)d_in[5];
    const float* orients = (const float*)d_in[6];
    const float* adims   = (const float*)d_in[7];
    float* out = (float*)d_out;

    decode_kernel<<<1024, 256, 0, stream>>>(obj1, cs1, bb1, obj2, cs2, bb2,
                                            orients, adims, out);
}

// Round 6
// 45.791 us; speedup vs baseline: 1.1460x; 1.0217x over previous
//
#include <hip/hip_runtime.h>

#define NLOC (1024 * 1024)          // H*W per head
#define HALF_PI 1.57079632679489662f
#define THRESH 0.9f

typedef float v4f __attribute__((ext_vector_type(4)));

__device__ __forceinline__ float sigmoidf_(float x) {
    return 1.0f / (1.0f + __expf(-x));
}

__device__ __forceinline__ void nt_store4(float* p, float a, float b, float c, float d) {
    v4f v = { a, b, c, d };
    __builtin_nontemporal_store(v, reinterpret_cast<v4f*>(p));
}

__device__ __forceinline__ void nt_copy4(float* g, const float* l) {
    v4f v = *reinterpret_cast<const v4f*>(l);
    __builtin_nontemporal_store(v, reinterpret_cast<v4f*>(g));
}

// Wave-scope LDS ordering: the transposes are CROSS-LANE data flow, so the
// compiler must not reorder LDS phases (cross-lane WAR/RAW is invisible to
// single-thread alias analysis — caused R5's corruption). HW DS pipe is
// in-order per wave, so this is ~free (no s_barrier, no vmcnt drain).
__device__ __forceinline__ void wave_lds_fence() {
    __builtin_amdgcn_fence(__ATOMIC_ACQ_REL, "wavefront");
    __builtin_amdgcn_wave_barrier();
}

// Persistent grid: 1024 blocks x 256 threads = 4 independent waves/block.
// Each wave owns a private 8 KB LDS slice and a 256-location tile
// (4 consecutive locations per lane), head 0 then head 1, with cross-head
// prefetch: head-1 obj+bb loads issue under head-0's boxes store phase,
// head-1 cs loads under head-0's scores store phase.
__global__ __launch_bounds__(256, 4) void decode_kernel(
    const float* __restrict__ obj1, const float* __restrict__ cs1, const float* __restrict__ bb1,
    const float* __restrict__ obj2, const float* __restrict__ cs2, const float* __restrict__ bb2,
    const float* __restrict__ orients, const float* __restrict__ adims,
    float* __restrict__ out)
{
    __shared__ float lds[4 * 2048];                 // 8 KB per wave

    const int tid  = threadIdx.x;
    const int wid  = tid >> 6;
    const int lane = tid & 63;
    const int wl   = ((int)blockIdx.x << 10) + (wid << 8);  // wave's first location
    const int n0   = wl + (lane << 2);                       // lane's first location
    float* buf = &lds[wid << 11];

    const float d0 = adims[0], d1 = adims[1], d2 = adims[2];
    const float or0 = orients[0], or1 = orients[1];
    float* ob0 = out;
    float* ob1 = out + (size_t)17 * NLOC;

    const float fi  = (float)(n0 >> 10) + 0.5f;
    const float fj0 = (float)(n0 & 1023) + 0.5f;

    // ================= head 0: issue loads =================
    float4 o0 = *reinterpret_cast<const float4*>(obj1 + n0);
    float4 b0[7];
#pragma unroll
    for (int c = 0; c < 7; ++c)
        b0[c] = *reinterpret_cast<const float4*>(bb1 + (size_t)c * NLOC + n0);
    float4 s0[8];
#pragma unroll
    for (int c = 0; c < 8; ++c)
        s0[c] = *reinterpret_cast<const float4*>(cs1 + (size_t)c * NLOC + n0);

    // ---- head 0: mask + boxes compute ----
    float ov0[4] = { o0.x, o0.y, o0.z, o0.w };
    float mk0[4];
    float bx[28];
#pragma unroll
    for (int t = 0; t < 4; ++t) {
        float m = (ov0[t] >= THRESH) ? 1.0f : 0.0f;
        mk0[t] = m;
        float fj = fj0 + (float)t;
        bx[t * 7 + 0] = (or0 + sigmoidf_(((const float*)&b0[0])[t]) * HALF_PI) * m;
        bx[t * 7 + 1] = (sigmoidf_(((const float*)&b0[1])[t]) + fi) * m;
        bx[t * 7 + 2] = (sigmoidf_(((const float*)&b0[2])[t]) + fj) * m;
        bx[t * 7 + 3] = sigmoidf_(((const float*)&b0[3])[t]) * m;
        bx[t * 7 + 4] = d0 * __expf(((const float*)&b0[4])[t]) * m;
        bx[t * 7 + 5] = d1 * __expf(((const float*)&b0[5])[t]) * m;
        bx[t * 7 + 6] = d2 * __expf(((const float*)&b0[6])[t]) * m;
    }
    nt_store4(ob0 + (size_t)15 * NLOC + n0,
              ov0[0] * mk0[0], ov0[1] * mk0[1], ov0[2] * mk0[2], ov0[3] * mk0[3]);
    nt_store4(ob0 + (size_t)16 * NLOC + n0, mk0[0], mk0[1], mk0[2], mk0[3]);

    // ---- head 0: boxes LDS write (stride 7 f4, conflict-free) ----
#pragma unroll
    for (int q = 0; q < 7; ++q)
        *reinterpret_cast<float4*>(&buf[lane * 28 + q * 4]) =
            make_float4(bx[q * 4 + 0], bx[q * 4 + 1], bx[q * 4 + 2], bx[q * 4 + 3]);

    // ---- issue head-1 obj+bb loads (hide under boxes0 read+store) ----
    float4 o1 = *reinterpret_cast<const float4*>(obj2 + n0);
    float4 b1[7];
#pragma unroll
    for (int c = 0; c < 7; ++c)
        b1[c] = *reinterpret_cast<const float4*>(bb2 + (size_t)c * NLOC + n0);

    wave_lds_fence();                               // boxes0 W -> R
    // ---- head 0: boxes read + coalesced nt store ----
    {
        float* gb = ob0 + (size_t)wl * 7;
#pragma unroll
        for (int q = 0; q < 7; ++q) {
            int w = 4 * (lane + 64 * q);
            nt_copy4(gb + w, &buf[w]);
        }
    }
    wave_lds_fence();                               // boxes0 R -> scores0 W

    // ---- head 0: scores LDS write (XOR swizzle) ----
#pragma unroll
    for (int q = 0; q < 8; ++q) {
        int t = q >> 1, c0 = (q & 1) * 4;
        float m = mk0[t];
        int f = lane * 8 + q;
        int p = f ^ ((f >> 3) & 7);
        *reinterpret_cast<float4*>(&buf[p * 4]) =
            make_float4(((const float*)&s0[c0 + 0])[t] * m, ((const float*)&s0[c0 + 1])[t] * m,
                        ((const float*)&s0[c0 + 2])[t] * m, ((const float*)&s0[c0 + 3])[t] * m);
    }

    // ---- issue head-1 cs loads (hide under scores0 read+store) ----
    float4 s1[8];
#pragma unroll
    for (int c = 0; c < 8; ++c)
        s1[c] = *reinterpret_cast<const float4*>(cs2 + (size_t)c * NLOC + n0);

    wave_lds_fence();                               // scores0 W -> R
    // ---- head 0: scores read + coalesced nt store ----
    {
        float* gs = ob0 + (size_t)7 * NLOC + (size_t)wl * 8;
#pragma unroll
        for (int q = 0; q < 8; ++q) {
            int f = lane + 64 * q;
            int p = f ^ ((f >> 3) & 7);
            nt_copy4(gs + 4 * f, &buf[p * 4]);
        }
    }
    wave_lds_fence();                               // scores0 R -> boxes1 W

    // ================= head 1 =================
    float ov1[4] = { o1.x, o1.y, o1.z, o1.w };
    float mk1[4];
#pragma unroll
    for (int t = 0; t < 4; ++t) {
        float m = (ov1[t] >= THRESH) ? 1.0f : 0.0f;
        mk1[t] = m;
        float fj = fj0 + (float)t;
        bx[t * 7 + 0] = (or1 + sigmoidf_(((const float*)&b1[0])[t]) * HALF_PI) * m;
        bx[t * 7 + 1] = (sigmoidf_(((const float*)&b1[1])[t]) + fi) * m;
        bx[t * 7 + 2] = (sigmoidf_(((const float*)&b1[2])[t]) + fj) * m;
        bx[t * 7 + 3] = sigmoidf_(((const float*)&b1[3])[t]) * m;
        bx[t * 7 + 4] = d0 * __expf(((const float*)&b1[4])[t]) * m;
        bx[t * 7 + 5] = d1 * __expf(((const float*)&b1[5])[t]) * m;
        bx[t * 7 + 6] = d2 * __expf(((const float*)&b1[6])[t]) * m;
    }
    nt_store4(ob1 + (size_t)15 * NLOC + n0,
              ov1[0] * mk1[0], ov1[1] * mk1[1], ov1[2] * mk1[2], ov1[3] * mk1[3]);
    nt_store4(ob1 + (size_t)16 * NLOC + n0, mk1[0], mk1[1], mk1[2], mk1[3]);

#pragma unroll
    for (int q = 0; q < 7; ++q)
        *reinterpret_cast<float4*>(&buf[lane * 28 + q * 4]) =
            make_float4(bx[q * 4 + 0], bx[q * 4 + 1], bx[q * 4 + 2], bx[q * 4 + 3]);

    wave_lds_fence();                               // boxes1 W -> R
    {
        float* gb = ob1 + (size_t)wl * 7;
#pragma unroll
        for (int q = 0; q < 7; ++q) {
            int w = 4 * (lane + 64 * q);
            nt_copy4(gb + w, &buf[w]);
        }
    }
    wave_lds_fence();                               // boxes1 R -> scores1 W

#pragma unroll
    for (int q = 0; q < 8; ++q) {
        int t = q >> 1, c0 = (q & 1) * 4;
        float m = mk1[t];
        int f = lane * 8 + q;
        int p = f ^ ((f >> 3) & 7);
        *reinterpret_cast<float4*>(&buf[p * 4]) =
            make_float4(((const float*)&s1[c0 + 0])[t] * m, ((const float*)&s1[c0 + 1])[t] * m,
                        ((const float*)&s1[c0 + 2])[t] * m, ((const float*)&s1[c0 + 3])[t] * m);
    }

    wave_lds_fence();                               // scores1 W -> R
    {
        float* gs = ob1 + (size_t)7 * NLOC + (size_t)wl * 8;
#pragma unroll
        for (int q = 0; q < 8; ++q) {
            int f = lane + 64 * q;
            int p = f ^ ((f >> 3) & 7);
            nt_copy4(gs + 4 * f, &buf[p * 4]);
        }
    }
}

extern "C" void kernel_launch(void* const* d_in, const int* in_sizes, int n_in,
                              void* d_out, int out_size, void* d_ws, size_t ws_size,
                              hipStream_t stream) {
    const float* obj1    = (const float*)d_in[0];
    const float* cs1     = (const float*)d_in[1];
    const float* bb1     = (const float*)d_in[2];
    const float* obj2    = (const float*)d_in[3];
    const float* cs2     = (const float*)d_in[4];
    const float* bb2     = (const float*)d_in[5];
    const float* orients = (const float*)d_in[6];
    const float* adims   = (const float*)d_in[7];
    float* out = (float*)d_out;

    decode_kernel<<<1024, 256, 0, stream>>>(obj1, cs1, bb1, obj2, cs2, bb2,
                                            orients, adims, out);
}